// Round 2
// baseline (2064.650 us; speedup 1.0000x reference)
//
#include <hip/hip_runtime.h>
#include <cstdint>
#include <cstddef>

typedef __bf16 bf16x8 __attribute__((ext_vector_type(8)));
typedef float f32x4 __attribute__((ext_vector_type(4)));

#define HD 256
#define TLEN 1000
#define NSTEP 999

// ws layout (bf16 elements): W1X | W1C | W2R | W3R | W4R, fragment-ordered
#define W1X_OFF 0
#define W1C_OFF 8192
#define W2R_OFF 16384
#define W3R_OFF 81920
#define W4R_OFF 147456
#define WS_ELEMS 151552

__device__ __forceinline__ void wg_barrier() {
  // LDS-only drain + barrier: do NOT force vmcnt(0) like __syncthreads does,
  // so the z/t prefetches and out-stores stay in flight across layer barriers.
  asm volatile("s_waitcnt lgkmcnt(0)\n\ts_barrier" ::: "memory");
}

// Repack fp32 weights -> bf16 MFMA A-fragments in ws.
// Layer-1 is algebraically folded:
//   pre1 = x*(W1[16+d]+W1[32+d]) + z_eff*(W1[24+d]+W1[40+d])
//        + x0*(W1[d]-W1[16+d]) + z0*(W1[8+d]-W1[24+d]) + b1
// W1X holds the per-step (x,z_eff) weights with a LANE-ALIGNED K layout:
//   q=0: j<4 -> x dims 0..3, q=1: x dims 4..7, q=2: z dims 0..3, q=3: z dims 4..7
// so each lane's B-frag is its OWN 4 state values (no cross-lane traffic).
// W1C holds the constant-part weights (consumed once pre-loop into c1init),
// with b1 at (q=0, j=4) fed by a constant-1 B element.
__global__ void prep_weights(const float* __restrict__ W1, const float* __restrict__ b1,
                             const float* __restrict__ W2, const float* __restrict__ W3,
                             const float* __restrict__ W4, __bf16* __restrict__ ws) {
  int tid = blockIdx.x * blockDim.x + threadIdx.x;
  if (tid >= WS_ELEMS) return;
  float val = 0.0f;
  if (tid < W1C_OFF) {                       // W1X: 8w x 2tt x 64lane x 8j
    int t = tid;
    int j = t & 7, lane = (t >> 3) & 63, tt = (t >> 9) & 1, w = (t >> 10) & 7;
    int q = lane >> 4;
    int n = w * 32 + tt * 16 + (lane & 15);
    if (j < 4) {
      int d = q * 4 + j;                     // 0..7 = x dim, 8..15 = z dim + 8
      if (q < 2) val = W1[(16 + d) * HD + n] + W1[(32 + d) * HD + n];
      else { int dz = d - 8; val = W1[(24 + dz) * HD + n] + W1[(40 + dz) * HD + n]; }
    }
  } else if (tid < W2R_OFF) {                // W1C: same shape as W1X
    int t = tid - W1C_OFF;
    int j = t & 7, lane = (t >> 3) & 63, tt = (t >> 9) & 1, w = (t >> 10) & 7;
    int q = lane >> 4;
    int n = w * 32 + tt * 16 + (lane & 15);
    if (j < 4) {
      int d = q * 4 + j;
      if (q < 2) val = W1[d * HD + n] - W1[(16 + d) * HD + n];
      else { int dz = d - 8; val = W1[(8 + dz) * HD + n] - W1[(24 + dz) * HD + n]; }
    } else if (q == 0 && j == 4) {
      val = b1[n];                           // bias row, fed by constant-1 at k=4
    }
  } else if (tid < W3R_OFF) {                // W2R: 8w x 8kb x 2tt x 64 x 8
    int t = tid - W2R_OFF;
    int j = t & 7, lane = (t >> 3) & 63, tt = (t >> 9) & 1, kb = (t >> 10) & 7, w = (t >> 13) & 7;
    int k = kb * 32 + ((lane >> 4) * 8) + j;
    int n = w * 32 + tt * 16 + (lane & 15);
    val = W2[k * HD + n];
  } else if (tid < W4R_OFF) {                // W3R
    int t = tid - W3R_OFF;
    int j = t & 7, lane = (t >> 3) & 63, tt = (t >> 9) & 1, kb = (t >> 10) & 7, w = (t >> 13) & 7;
    int k = kb * 32 + ((lane >> 4) * 8) + j;
    int n = w * 32 + tt * 16 + (lane & 15);
    val = W3[k * HD + n];
  } else {                                   // W4R: 8kb x 64 x 8, N padded 8->16 with zeros
    int t = tid - W4R_OFF;
    int j = t & 7, lane = (t >> 3) & 63, kb = (t >> 9) & 7;
    int k = kb * 32 + ((lane >> 4) * 8) + j;
    int n = lane & 15;
    val = (n < 8) ? W4[k * 8 + n] : 0.0f;
  }
  ws[tid] = (__bf16)val;
}

// 128 WGs x 8 batch rows; 8 waves x 32 hidden cols; 2 waves/SIMD.
// Post-mortem r1: the step cost is LDS *data bandwidth* (each layer = every
// wave reads the whole h matrix). This version (a) exec-masks all h reads and
// writes to the 8 live B-columns (dead lanes keep zero frags -> half the bank
// traffic), (b) reverts layer 4 to per-wave partial + p4 reduce (one full-h
// read per step less than r1), keeping the register x-state and folded L1.
__global__ __launch_bounds__(512, 2) void ode_main(
    const float* __restrict__ t_g, const float* __restrict__ x_g,
    const float* __restrict__ z_g, const float* __restrict__ ev_g,
    const float* __restrict__ zj_g, const float* __restrict__ b2_g,
    const float* __restrict__ b3_g, const float* __restrict__ b4_g,
    const __bf16* __restrict__ ws, float* __restrict__ out) {
  // triple-buffered hidden activations: L1->hA, L2: hA->hB, L3: hB->hC(own cols),
  // L4 partial reads hC own cols. All WAR pairs are separated by >=2 barriers.
  __shared__ __align__(16) __bf16 hA[16 * 264];
  __shared__ __align__(16) __bf16 hB[16 * 264];
  __shared__ __align__(16) __bf16 hC[16 * 264];
  __shared__ __align__(16) float p4[8 * 128];   // [wave][bcol*8 + q*4 .. +3]

  const int tid  = threadIdx.x;
  const int lane = tid & 63;
  const int wid  = tid >> 6;     // 8 waves; wave w owns hidden cols [32w, 32w+32)
  const int bcol = lane & 15;    // B/C-operand column; batch row if < 8, dead otherwise
  const int q    = lane >> 4;    // quad
  const int b0   = blockIdx.x * 8;
  const bool live = bcol < 8;
  const size_t gb = (size_t)(b0 + (live ? bcol : 0));  // safe base; stores masked by `live`

  // ---- resident weight fragments ----
  const bf16x8* wsv = (const bf16x8*)ws;
  bf16x8 w1f[2], w2f[8][2], w3f[8][2];
#pragma unroll
  for (int tt = 0; tt < 2; ++tt)
    w1f[tt] = wsv[(W1X_OFF / 8) + (wid * 2 + tt) * 64 + lane];
#pragma unroll
  for (int kb = 0; kb < 8; ++kb)
#pragma unroll
    for (int tt = 0; tt < 2; ++tt) {
      w2f[kb][tt] = wsv[(W2R_OFF / 8) + ((wid * 8 + kb) * 2 + tt) * 64 + lane];
      w3f[kb][tt] = wsv[(W3R_OFF / 8) + ((wid * 8 + kb) * 2 + tt) * 64 + lane];
    }
  // W4 k-slice for this wave only: k in [32*wid, 32*wid+32)
  bf16x8 w4f = wsv[(W4R_OFF / 8) + wid * 64 + lane];

  // biases as C-init: lane's 4 C rows are hidden n = wid*32 + tt*16 + q*4 + e
  f32x4 b2v[2], b3v[2];
#pragma unroll
  for (int tt = 0; tt < 2; ++tt) {
    int n0 = wid * 32 + tt * 16 + q * 4;
    b2v[tt] = *(const f32x4*)(b2_g + n0);
    b3v[tt] = *(const f32x4*)(b3_g + n0);
  }
  f32x4 b4v = {0.f, 0.f, 0.f, 0.f};
  if (q < 2) b4v = *(const f32x4*)(b4_g + q * 4);   // C rows q*4+e < 8 are the live out dims

  // ---- per-lane initial quarter: q0:x0[0:4] q1:x0[4:8] q2:z0[0:4] q3:z0[4:8] ----
  f32x4 init4 = {0.f, 0.f, 0.f, 0.f};
  if (live) {
    const float* p = (q < 2) ? (x_g + gb * (TLEN * 8) + q * 4)
                             : (z_g + gb * (TLEN * 8) + (q - 2) * 4);
    init4 = *(const f32x4*)p;
  }
  float ev1 = 0.f;
  bf16x8 zjh;
#pragma unroll
  for (int e = 0; e < 8; ++e) zjh[e] = (__bf16)0.f;
  if (q >= 2 && live) {                       // z-producing quads own their zj quarter
    ev1 = ev_g[gb];
    f32x4 zj4 = *(const f32x4*)(zj_g + gb * 8 + (q - 2) * 4);
#pragma unroll
    for (int e = 0; e < 4; ++e) zjh[e] = (__bf16)zj4[e];
  }

  float t0 = t_g[0];

  // ---- c1init: step-invariant layer-1 part (x0, z0, b1 terms) via one MFMA ----
  f32x4 c1init[2];
  {
    bf16x8 cb;
#pragma unroll
    for (int e = 0; e < 8; ++e) cb[e] = (__bf16)0.f;
#pragma unroll
    for (int e = 0; e < 4; ++e) cb[e] = (__bf16)init4[e];
    if (q == 0) cb[4] = (__bf16)1.0f;        // feeds the b1 row of W1C
#pragma unroll
    for (int tt = 0; tt < 2; ++tt) {
      bf16x8 w1cf = wsv[(W1C_OFF / 8) + (wid * 2 + tt) * 64 + lane];
      f32x4 z4 = {0.f, 0.f, 0.f, 0.f};
      c1init[tt] = __builtin_amdgcn_mfma_f32_16x16x32_bf16(w1cf, cb, z4, 0, 0, 0);
    }
  }

  // x state lives in C-layout registers (q<2: dims q*4..q*4+3 of own bcol);
  // myfrag is the lane's layer-1 B-frag (its OWN quarter: x for q<2, z_eff for q>=2)
  f32x4 xc4 = {0.f, 0.f, 0.f, 0.f};
  if (q < 2) xc4 = init4;
  bf16x8 zfrag;
#pragma unroll
  for (int e = 0; e < 8; ++e) zfrag[e] = (__bf16)0.f;
  bf16x8 myfrag = zfrag;
  if (q < 2) {
#pragma unroll
    for (int e = 0; e < 4; ++e) myfrag[e] = (__bf16)init4[e];
  } else {
    bool jmp0 = (t0 >= ev1);
#pragma unroll
    for (int e = 0; e < 4; ++e) myfrag[e] = jmp0 ? zjh[e] : (__bf16)init4[e];
  }

  if (wid == 0 && q < 2 && live)
    *(f32x4*)(out + gb * (TLEN * 8) + q * 4) = init4;   // sol[:,0] = x0

  float tc = t0;

  // persistent masked-read destinations: dead lanes keep ZEROS forever (finite;
  // their MFMA columns 8-15 are never consumed) -> no undef, no NaN.
  bf16x8 bfr[8];
#pragma unroll
  for (int kb = 0; kb < 8; ++kb) bfr[kb] = zfrag;
  bf16x8 h4r = zfrag;

  auto layer = [&](const __bf16* src, __bf16* dst, const bf16x8 (*wf)[2], const f32x4* bv) {
    const bf16x8* hp = (const bf16x8*)src;
    if (live) {   // exec-masked reads: dead lanes generate no LDS bank traffic
#pragma unroll
      for (int kb = 0; kb < 8; ++kb) bfr[kb] = hp[bcol * 33 + kb * 4 + q];
    }
#pragma unroll
    for (int tt = 0; tt < 2; ++tt) {
      f32x4 c0 = bv[tt];
      f32x4 c1 = {0.f, 0.f, 0.f, 0.f};
      // split the 8-deep accumulation into two independent 4-chains
#pragma unroll
      for (int kb = 0; kb < 4; ++kb)
        c0 = __builtin_amdgcn_mfma_f32_16x16x32_bf16(wf[kb][tt], bfr[kb], c0, 0, 0, 0);
#pragma unroll
      for (int kb = 4; kb < 8; ++kb)
        c1 = __builtin_amdgcn_mfma_f32_16x16x32_bf16(wf[kb][tt], bfr[kb], c1, 0, 0, 0);
      union { __bf16 h4[4]; unsigned long long u; } pk;
#pragma unroll
      for (int e = 0; e < 4; ++e) {
        float v = c0[e] + c1[e];
        v = (v > 0.f) ? v : (__expf(v) - 1.0f);  // ELU
        pk.h4[e] = (__bf16)v;
      }
      if (live)
        *(unsigned long long*)(dst + bcol * 264 + wid * 32 + tt * 16 + q * 4) = pk.u;
    }
  };

#pragma unroll 1
  for (int i = 0; i < NSTEP; ++i) {
    float tn = t_g[i + 1];
    f32x4 zp4 = {0.f, 0.f, 0.f, 0.f};
    if (q >= 2 && live)  // prefetch own quarter of z[:, i+1]; consumed at step end
      zp4 = *(const f32x4*)(z_g + (gb * TLEN + (size_t)(i + 1)) * 8 + (q - 2) * 4);

    // ---- phase 1: layer 1 — pure-register B-frag, 1 MFMA per tt ----
#pragma unroll
    for (int tt = 0; tt < 2; ++tt) {
      f32x4 c = __builtin_amdgcn_mfma_f32_16x16x32_bf16(w1f[tt], myfrag, c1init[tt], 0, 0, 0);
      union { __bf16 h4[4]; unsigned long long u; } pk;
#pragma unroll
      for (int e = 0; e < 4; ++e) {
        float v = c[e];
        v = (v > 0.f) ? v : (__expf(v) - 1.0f);
        pk.h4[e] = (__bf16)v;
      }
      if (live)
        *(unsigned long long*)(hA + bcol * 264 + wid * 32 + tt * 16 + q * 4) = pk.u;
    }
    wg_barrier();
    layer(hA, hB, w2f, b2v);   // phase 2: layer 2
    wg_barrier();
    layer(hB, hC, w3f, b3v);   // phase 3: layer 3 (own cols written to hC)

    // ---- phase 3b (no barrier): layer-4 partial on OWN 32 cols ----
    // Same-wave RAW through LDS (we read back only rows this wave just wrote).
    {
      if (live) h4r = ((const bf16x8*)hC)[bcol * 33 + wid * 4 + q];
      f32x4 c = {0.f, 0.f, 0.f, 0.f};
      c = __builtin_amdgcn_mfma_f32_16x16x32_bf16(w4f, h4r, c, 0, 0, 0);
      if (q < 2 && live)  // 16 active lanes, starts 16B-aligned, 2-way aliasing (free)
        *(f32x4*)(p4 + wid * 128 + bcol * 8 + q * 4) = c;
    }
    wg_barrier();

    // ---- phase 4: per-lane reduce of 8 partials + Euler in registers ----
    float dt = tn - tc;
    if (live) {
      if (q < 2) {
        const float* pp = p4 + bcol * 8 + q * 4;
        f32x4 a0 = *(const f32x4*)(pp + 0 * 128);
        f32x4 a1 = *(const f32x4*)(pp + 1 * 128);
        f32x4 a2 = *(const f32x4*)(pp + 2 * 128);
        f32x4 a3 = *(const f32x4*)(pp + 3 * 128);
        f32x4 a4 = *(const f32x4*)(pp + 4 * 128);
        f32x4 a5 = *(const f32x4*)(pp + 5 * 128);
        f32x4 a6 = *(const f32x4*)(pp + 6 * 128);
        f32x4 a7 = *(const f32x4*)(pp + 7 * 128);
        f32x4 s = ((a0 + a1) + (a2 + a3)) + ((a4 + a5) + (a6 + a7));
        f32x4 xn;
#pragma unroll
        for (int e = 0; e < 4; ++e) xn[e] = xc4[e] + dt * (s[e] + b4v[e]);
        xc4 = xn;
        if (wid == 0)    // one wave stores; fire-and-forget (no vmcnt at barriers)
          *(f32x4*)(out + gb * (TLEN * 8) + (size_t)(i + 1) * 8 + q * 4) = xn;
#pragma unroll
        for (int e = 0; e < 4; ++e) myfrag[e] = (__bf16)xn[e];
      } else {
        bool jmp = (tn >= ev1);
#pragma unroll
        for (int e = 0; e < 4; ++e) myfrag[e] = jmp ? zjh[e] : (__bf16)zp4[e];
      }
    }
    tc = tn;
  }
}

extern "C" void kernel_launch(void* const* d_in, const int* in_sizes, int n_in,
                              void* d_out, int out_size, void* d_ws, size_t ws_size,
                              hipStream_t stream) {
  const float* t  = (const float*)d_in[0];
  const float* x  = (const float*)d_in[1];
  const float* z  = (const float*)d_in[2];
  const float* ev = (const float*)d_in[3];
  const float* zj = (const float*)d_in[4];
  const float* W1 = (const float*)d_in[5];
  const float* b1 = (const float*)d_in[6];
  const float* W2 = (const float*)d_in[7];
  const float* b2 = (const float*)d_in[8];
  const float* W3 = (const float*)d_in[9];
  const float* b3 = (const float*)d_in[10];
  const float* W4 = (const float*)d_in[11];
  const float* b4 = (const float*)d_in[12];
  __bf16* ws = (__bf16*)d_ws;
  float* out = (float*)d_out;

  prep_weights<<<592, 256, 0, stream>>>(W1, b1, W2, W3, W4, ws);
  ode_main<<<128, 512, 0, stream>>>(t, x, z, ev, zj, b2, b3, b4, ws, out);
}

// Round 4
// 1670.724 us; speedup vs baseline: 1.2358x; 1.2358x over previous
//
#include <hip/hip_runtime.h>
#include <cstdint>
#include <cstddef>

typedef __bf16 bf16x8 __attribute__((ext_vector_type(8)));
typedef float f32x4 __attribute__((ext_vector_type(4)));

#define HD 256
#define TLEN 1000
#define NSTEP 999
#define BTILE 4

// ws layout (bf16 elements): W1R | W2R | W3R | W4R, fragment-ordered
#define W1R_OFF 0
#define W2R_OFF 16384
#define W3R_OFF 81920
#define W4R_OFF 147456
#define WS_ELEMS 151552

__device__ __forceinline__ void wg_barrier() {
  // LDS-only drain + barrier: do NOT force vmcnt(0) like __syncthreads does,
  // so the z-prefetch / out-stores stay in flight across layer barriers.
  asm volatile("s_waitcnt lgkmcnt(0)\n\ts_barrier" ::: "memory");
}

// Repack fp32 weights -> bf16 MFMA A-fragments in ws (v0 layout).
// Fragment element for (w,kb,tt,lane,j): k = kb*32 + (lane>>4)*8 + j ; n = w*32 + tt*16 + (lane&15)
// value = W[k][n] (b1 folded into W1 padded row k==48).
__global__ void prep_weights(const float* __restrict__ W1, const float* __restrict__ b1,
                             const float* __restrict__ W2, const float* __restrict__ W3,
                             const float* __restrict__ W4, __bf16* __restrict__ ws) {
  int tid = blockIdx.x * blockDim.x + threadIdx.x;
  if (tid >= WS_ELEMS) return;
  float val = 0.0f;
  if (tid < W2R_OFF) {                       // W1R: 8w x 2kb x 2tt x 64lane x 8j
    int t = tid;
    int j = t & 7, lane = (t >> 3) & 63, tt = (t >> 9) & 1, kb = (t >> 10) & 1, w = (t >> 11) & 7;
    int k = kb * 32 + ((lane >> 4) * 8) + j;
    int n = w * 32 + tt * 16 + (lane & 15);
    if (k < 48) val = W1[k * HD + n];
    else if (k == 48) val = b1[n];           // bias folded via constant-1 input at k=48
  } else if (tid < W3R_OFF) {                // W2R: 8w x 8kb x 2tt x 64 x 8
    int t = tid - W2R_OFF;
    int j = t & 7, lane = (t >> 3) & 63, tt = (t >> 9) & 1, kb = (t >> 10) & 7, w = (t >> 13) & 7;
    int k = kb * 32 + ((lane >> 4) * 8) + j;
    int n = w * 32 + tt * 16 + (lane & 15);
    val = W2[k * HD + n];
  } else if (tid < W4R_OFF) {                // W3R
    int t = tid - W3R_OFF;
    int j = t & 7, lane = (t >> 3) & 63, tt = (t >> 9) & 1, kb = (t >> 10) & 7, w = (t >> 13) & 7;
    int k = kb * 32 + ((lane >> 4) * 8) + j;
    int n = w * 32 + tt * 16 + (lane & 15);
    val = W3[k * HD + n];
  } else {                                   // W4R: 8kb x 64 x 8, N padded 8->16 with zeros
    int t = tid - W4R_OFF;
    int j = t & 7, lane = (t >> 3) & 63, kb = (t >> 9) & 7;
    int k = kb * 32 + ((lane >> 4) * 8) + j;
    int n = lane & 15;
    val = (n < 8) ? W4[k * 8 + n] : 0.0f;
  }
  ws[tid] = (__bf16)val;
}

// v0 schedule (proven fastest) + two LDS-residency cuts, nothing else:
//  (a) batch tile 4 -> 256 WGs -> all 256 CUs; live B-cols = 4 of 16.
//  (b) exec-mask every h-matrix LDS read/write to live cols; dead lanes keep
//      persistent zero fragments (masked lanes issue no LDS bank requests —
//      r2's SQ_LDS_BANK_CONFLICT 3.3x drop proved the mechanism).
// Dead columns carry exact zeros end-to-end (phase-4 Euler guarded to m<BTILE).
__global__ __launch_bounds__(512, 2) void ode_main(
    const float* __restrict__ t_g, const float* __restrict__ x_g,
    const float* __restrict__ z_g, const float* __restrict__ ev_g,
    const float* __restrict__ zj_g, const float* __restrict__ b2_g,
    const float* __restrict__ b3_g, const float* __restrict__ b4_g,
    const __bf16* __restrict__ ws, float* __restrict__ out) {
  __shared__ __align__(16) __bf16 h_a[16 * 264];   // 16 rows kept (4 live), row 528B
  __shared__ __align__(16) __bf16 h_b[16 * 264];
  __shared__ __align__(16) float p4[8 * 16 * 8];   // [wave][bcol][dim]
  __shared__ __align__(16) float x_cur[16 * 12];
  __shared__ __align__(16) float z_eff[16 * 12];
  __shared__ __align__(16) float x0s[16 * 12];
  __shared__ __align__(16) float z0s[16 * 12];
  __shared__ __align__(16) float zjs[16 * 12];
  __shared__ float evs[16];

  const int tid  = threadIdx.x;
  const int lane = tid & 63;
  const int wid  = tid >> 6;     // 8 waves; wave w owns hidden cols [32w, 32w+32)
  const int bcol = lane & 15;    // B/C-operand column; batch row if < BTILE, dead otherwise
  const int q    = lane >> 4;    // quad
  const int b0   = blockIdx.x * BTILE;
  const bool live = bcol < BTILE;

  // ---- stage per-batch constants (rows >= BTILE zeroed: dead cols stay exact 0) ----
  if (tid < 128) {
    int m = tid >> 3, d = tid & 7;
    if (m < BTILE) {
      size_t gb = (size_t)(b0 + m);
      float x0 = x_g[gb * (TLEN * 8) + d];
      float z0 = z_g[gb * (TLEN * 8) + d];
      x0s[m * 12 + d] = x0;
      z0s[m * 12 + d] = z0;
      x_cur[m * 12 + d] = x0;
      zjs[m * 12 + d] = zj_g[gb * 8 + d];
      out[gb * (TLEN * 8) + d] = x0;         // sol[:,0] = x0
      if (d == 0) evs[m] = ev_g[gb];
    } else {
      x0s[m * 12 + d] = 0.f;
      z0s[m * 12 + d] = 0.f;
      x_cur[m * 12 + d] = 0.f;
      zjs[m * 12 + d] = 0.f;
      if (d == 0) evs[m] = 0.f;
    }
  }
  __syncthreads();

  if (tid < 128) {  // z_eff for step 0 (rows >= BTILE resolve to 0)
    int m = tid >> 3, d = tid & 7;
    float t0 = t_g[0];
    z_eff[m * 12 + d] = (t0 >= evs[m]) ? zjs[m * 12 + d] : z0s[m * 12 + d];
  }

  // ---- resident weight fragments (A-operand layout) ----
  const bf16x8* wsv = (const bf16x8*)ws;
  bf16x8 w1f[2][2], w2f[8][2], w3f[8][2];
#pragma unroll
  for (int kb = 0; kb < 2; ++kb)
#pragma unroll
    for (int tt = 0; tt < 2; ++tt)
      w1f[kb][tt] = wsv[(W1R_OFF / 8) + ((wid * 2 + kb) * 2 + tt) * 64 + lane];
#pragma unroll
  for (int kb = 0; kb < 8; ++kb)
#pragma unroll
    for (int tt = 0; tt < 2; ++tt) {
      w2f[kb][tt] = wsv[(W2R_OFF / 8) + ((wid * 8 + kb) * 2 + tt) * 64 + lane];
      w3f[kb][tt] = wsv[(W3R_OFF / 8) + ((wid * 8 + kb) * 2 + tt) * 64 + lane];
    }
  // W4 k-slice for this wave: k in [32*wid, 32*wid+32)
  bf16x8 w4f = wsv[(W4R_OFF / 8) + wid * 64 + lane];

  // biases as C-init: lane's 4 C rows are hidden n = wid*32 + tt*16 + q*4 + e
  f32x4 b2v[2], b3v[2];
#pragma unroll
  for (int tt = 0; tt < 2; ++tt) {
    int n0 = wid * 32 + tt * 16 + q * 4;
    b2v[tt] = *(const f32x4*)(b2_g + n0);
    b3v[tt] = *(const f32x4*)(b3_g + n0);
  }
  float b4l = (tid < 64) ? b4_g[tid & 7] : 0.0f;

  // wave-2 personals (z_eff producer): lanes 0..BTILE*4-1 cover (m 0..BTILE-1) x (d pairs)
  const int m1 = lane >> 2;          // batch row
  const int d0 = (lane & 3) * 2;
  float2 zjf = make_float2(0.f, 0.f);
  float ev1 = 0.f;
  const bool zprod = (wid == 2) && (lane < BTILE * 4);
  if (zprod) {
    zjf.x = zjs[m1 * 12 + d0];
    zjf.y = zjs[m1 * 12 + d0 + 1];
    ev1 = evs[m1];
  }

  // layer-1 per-lane B-frag constants:
  // q=0: k=0..7   -> x0 (const)          q=1: k=8..15  -> z0 (const)
  // q=2: k=16..23 -> x_cur - x0          q=3: k=24..31 -> z_eff - z0
  f32x4 sub0, sub1;
  bf16x8 a0c;
  {
    const float* base = ((q & 1) ? z0s : x0s) + bcol * 12;
    f32x4 r0 = *(const f32x4*)(base);
    f32x4 r1 = *(const f32x4*)(base + 4);
    sub0 = r0; sub1 = r1;
#pragma unroll
    for (int e = 0; e < 4; ++e) { a0c[e] = (__bf16)r0[e]; a0c[e + 4] = (__bf16)r1[e]; }
  }
  bf16x8 zf;
#pragma unroll
  for (int e = 0; e < 8; ++e) zf[e] = (__bf16)0.f;
  bf16x8 k48f = zf;
  k48f[0] = (__bf16)1.0f;  // constant-1 input at padded k=48 -> adds b1

  __syncthreads();

  float tc = t_g[0];

  // persistent masked-read destinations: dead lanes keep zeros forever.
  bf16x8 bfr[8];
#pragma unroll
  for (int kb = 0; kb < 8; ++kb) bfr[kb] = zf;
  bf16x8 h4r = zf;

  auto layer = [&](const __bf16* src, __bf16* dst, const bf16x8 (*wf)[2], const f32x4* bv) {
    const bf16x8* hp = (const bf16x8*)src;
    if (live) {   // masked reads: dead lanes generate no LDS traffic
#pragma unroll
      for (int kb = 0; kb < 8; ++kb) bfr[kb] = hp[bcol * 33 + kb * 4 + q];  // ds_read_b128 x8
    }
#pragma unroll
    for (int tt = 0; tt < 2; ++tt) {
      f32x4 c = bv[tt];
#pragma unroll
      for (int kb = 0; kb < 8; ++kb)
        c = __builtin_amdgcn_mfma_f32_16x16x32_bf16(wf[kb][tt], bfr[kb], c, 0, 0, 0);
      union { __bf16 h4[4]; unsigned long long u; } pk;
#pragma unroll
      for (int e = 0; e < 4; ++e) {
        float v = c[e];
        v = (v > 0.f) ? v : (__expf(v) - 1.0f);  // ELU
        pk.h4[e] = (__bf16)v;
      }
      // 4 consecutive hidden cols for batch bcol -> one ds_write_b64
      if (live)
        *(unsigned long long*)(dst + bcol * 264 + wid * 32 + tt * 16 + q * 4) = pk.u;
    }
  };

#pragma unroll 1
  for (int i = 0; i < NSTEP; ++i) {
    float tn = t_g[i + 1];
    float2 zpre = make_float2(0.f, 0.f);
    if (zprod)  // prefetch z[:, i+1]; consumed in phase 4 of this step
      zpre = *(const float2*)(z_g + ((size_t)(b0 + m1) * TLEN + (i + 1)) * 8 + d0);

    // ---- phase 1: layer 1 (K padded 48->64, bias via k=48) ----
    {
      const float* rp = ((q & 1) ? z_eff : x_cur) + bcol * 12;
      f32x4 r0 = *(const f32x4*)(rp);
      f32x4 r1 = *(const f32x4*)(rp + 4);
      bf16x8 f0, f1;
      if (q < 2) {
        f0 = a0c;
#pragma unroll
        for (int e = 0; e < 4; ++e) { f1[e] = (__bf16)r0[e]; f1[e + 4] = (__bf16)r1[e]; }
      } else {
#pragma unroll
        for (int e = 0; e < 4; ++e) {
          f0[e] = (__bf16)(r0[e] - sub0[e]);
          f0[e + 4] = (__bf16)(r1[e] - sub1[e]);
        }
        f1 = (q == 2) ? k48f : zf;
      }
#pragma unroll
      for (int tt = 0; tt < 2; ++tt) {
        f32x4 c = {0.f, 0.f, 0.f, 0.f};
        c = __builtin_amdgcn_mfma_f32_16x16x32_bf16(w1f[0][tt], f0, c, 0, 0, 0);
        c = __builtin_amdgcn_mfma_f32_16x16x32_bf16(w1f[1][tt], f1, c, 0, 0, 0);
        union { __bf16 h4[4]; unsigned long long u; } pk;
#pragma unroll
        for (int e = 0; e < 4; ++e) {
          float v = c[e];
          v = (v > 0.f) ? v : (__expf(v) - 1.0f);
          pk.h4[e] = (__bf16)v;
        }
        if (live)
          *(unsigned long long*)(h_a + bcol * 264 + wid * 32 + tt * 16 + q * 4) = pk.u;
      }
    }
    wg_barrier();
    layer(h_a, h_b, w2f, b2v);   // phase 2: layer 2
    wg_barrier();
    layer(h_b, h_a, w3f, b3v);   // phase 3: layer 3 (h3 -> h_a)

    // ---- phase 3b (fused, no barrier): layer-4 partial on OWN 32 columns ----
    {
      const bf16x8* hp = (const bf16x8*)h_a;
      if (live) h4r = hp[bcol * 33 + wid * 4 + q];
      f32x4 c = {0.f, 0.f, 0.f, 0.f};
      c = __builtin_amdgcn_mfma_f32_16x16x32_bf16(w4f, h4r, c, 0, 0, 0);
      if (q < 2 && live)  // valid out rows n = q*4+e < 8
        *(f32x4*)(p4 + wid * 128 + bcol * 8 + q * 4) = c;
    }
    wg_barrier();

    // ---- phase 4: reduce + Euler (wave 0, rows < BTILE), z_eff(i+1) (wave 2) ----
    float dt = tn - tc;
    if (tid < 64) {
      int m = tid >> 3, d = tid & 7;
      if (m < BTILE) {                 // live batch rows only; rows >= BTILE stay 0
        float s = b4l;
#pragma unroll
        for (int j = 0; j < 8; ++j) s += p4[j * 128 + m * 8 + d];
        float xn = x_cur[m * 12 + d] + dt * s;
        x_cur[m * 12 + d] = xn;
        out[(size_t)(b0 + m) * (TLEN * 8) + (size_t)(i + 1) * 8 + d] = xn;
      }
    } else if (zprod) {
      bool jmp = (tn >= ev1);
      float2 zev = make_float2(jmp ? zjf.x : zpre.x, jmp ? zjf.y : zpre.y);
      *(float2*)(z_eff + m1 * 12 + d0) = zev;
    }
    tc = tn;
    wg_barrier();
  }
}

extern "C" void kernel_launch(void* const* d_in, const int* in_sizes, int n_in,
                              void* d_out, int out_size, void* d_ws, size_t ws_size,
                              hipStream_t stream) {
  const float* t  = (const float*)d_in[0];
  const float* x  = (const float*)d_in[1];
  const float* z  = (const float*)d_in[2];
  const float* ev = (const float*)d_in[3];
  const float* zj = (const float*)d_in[4];
  const float* W1 = (const float*)d_in[5];
  const float* b1 = (const float*)d_in[6];
  const float* W2 = (const float*)d_in[7];
  const float* b2 = (const float*)d_in[8];
  const float* W3 = (const float*)d_in[9];
  const float* b3 = (const float*)d_in[10];
  const float* W4 = (const float*)d_in[11];
  const float* b4 = (const float*)d_in[12];
  __bf16* ws = (__bf16*)d_ws;
  float* out = (float*)d_out;

  prep_weights<<<592, 256, 0, stream>>>(W1, b1, W2, W3, W4, ws);
  ode_main<<<256, 512, 0, stream>>>(t, x, z, ev, zj, b2, b3, b4, ws, out);
}